// Round 1
// baseline (1291.690 us; speedup 1.0000x reference)
//
#include <hip/hip_runtime.h>
#include <hip/hip_bf16.h>
#include <math.h>

#define Tn 8
#define Hn 32
#define Wn 32
#define Pn 8192      // Tn*Hn*Wn
#define Cn 256
#define CINn 128
#define NTAP 147     // 3*7*7
#define NQn 256

__device__ __forceinline__ float gelu_f(float v) {
    // jax.nn.gelu approximate=True (tanh)
    return 0.5f * v * (1.0f + tanhf(0.7978845608028654f * (v + 0.044715f * v * v * v)));
}

// ---- transpose per-block kernels to [tap][c]; fold 0.9*tanh into A ----
__global__ void prep_kernels_k(const float* __restrict__ A, const float* __restrict__ B,
                               float* __restrict__ AT, float* __restrict__ BT) {
    int tap = blockIdx.x;   // 0..146
    int c = threadIdx.x;    // 0..255
    AT[tap * Cn + c] = 0.9f * tanhf(A[c * NTAP + tap]);
    BT[tap * Cn + c] = B[c * NTAP + tap];
}

// ---- depthwise 3x7x7 circular conv over (t,h,w), channels-last float4 ----
// y = k (*) src ; h = (first ? y : h + y)
__global__ __launch_bounds__(512) void conv_dw_k(
        const float4* __restrict__ src4, const float4* __restrict__ kT4,
        float4* __restrict__ y4, float4* __restrict__ h4, int first) {
    const int t = blockIdx.x >> 5;   // 0..7
    const int h = blockIdx.x & 31;   // 0..31
    const int tid = (int)threadIdx.x;
    const int c4 = tid & 63;         // channel quad 0..63
    const int w0 = (tid >> 6) * 4;   // 0,4,...,28

    float4 acc[4];
#pragma unroll
    for (int j = 0; j < 4; ++j) acc[j] = make_float4(0.f, 0.f, 0.f, 0.f);

#pragma unroll
    for (int kt = 0; kt < 3; ++kt) {
        const int tp = (t - kt + 1 + 8) & 7;             // (t - (kt-1)) mod 8
#pragma unroll 1
        for (int kh = 0; kh < 7; ++kh) {
            const int hp = (h - kh + 3 + 32) & 31;       // (h - (kh-3)) mod 32
            const int rowbase = (tp * Hn + hp) * (Wn * 64);
            float4 xr[10];                               // x[(w0-3 .. w0+6) mod 32]
#pragma unroll
            for (int m = 0; m < 10; ++m) {
                const int ww = (w0 + m + 29) & 31;       // (w0 - 3 + m) mod 32
                xr[m] = src4[rowbase + ww * 64 + c4];
            }
#pragma unroll
            for (int kw = 0; kw < 7; ++kw) {
                const float4 k4 = kT4[((kt * 7 + kh) * 7 + kw) * 64 + c4];
#pragma unroll
                for (int j = 0; j < 4; ++j) {
                    const float4 xv = xr[j + 6 - kw];    // x[(w - (kw-3)) mod 32]
                    acc[j].x = fmaf(k4.x, xv.x, acc[j].x);
                    acc[j].y = fmaf(k4.y, xv.y, acc[j].y);
                    acc[j].z = fmaf(k4.z, xv.z, acc[j].z);
                    acc[j].w = fmaf(k4.w, xv.w, acc[j].w);
                }
            }
        }
    }

    const int outbase = (t * Hn + h) * (Wn * 64);
#pragma unroll
    for (int j = 0; j < 4; ++j) {
        const int idx = outbase + (w0 + j) * 64 + c4;
        y4[idx] = acc[j];
        if (first) {
            h4[idx] = acc[j];
        } else {
            float4 o = h4[idx];
            o.x += acc[j].x; o.y += acc[j].y; o.z += acc[j].z; o.w += acc[j].w;
            h4[idx] = o;
        }
    }
}

// ---- generic f32 GEMM: C = f(A[M,K] @ W[K,N] + bias) ----
// MODE 0: C = v ; MODE 1: C = gelu(v) ; MODE 2: C += v (residual in C)
template <int MODE>
__global__ __launch_bounds__(256) void gemm_f32_k(
        const float* __restrict__ A, const float* __restrict__ W,
        const float* __restrict__ bias, float* __restrict__ C,
        int M, int N, int K) {
    __shared__ float As[16][68];   // [k][m], padded for b128-aligned reads
    __shared__ float Bs[16][64];   // [k][n]
    const int tid = (int)threadIdx.x;
    const int tx = tid & 15, ty = tid >> 4;
    const int bm = blockIdx.y, bn = blockIdx.x;

    float acc[4][4];
#pragma unroll
    for (int i = 0; i < 4; ++i)
#pragma unroll
        for (int j = 0; j < 4; ++j) acc[i][j] = 0.f;

    const int ra = tid >> 2;          // 0..63: A-tile row
    const int ca = (tid & 3) * 4;     // 0,4,8,12: A-tile col (k)
    const int rw = tid >> 4;          // 0..15: W-tile row (k)
    const int cw = (tid & 15) * 4;    // 0..60: W-tile col
    const float* Ap = A + (size_t)(bm * 64 + ra) * K + ca;
    const float* Wp = W + (size_t)rw * N + bn * 64 + cw;

    for (int kb = 0; kb < K; kb += 16) {
        const float4 av = *(const float4*)(Ap + kb);
        const float4 wv = *(const float4*)(Wp + (size_t)kb * N);
        As[ca + 0][ra] = av.x;
        As[ca + 1][ra] = av.y;
        As[ca + 2][ra] = av.z;
        As[ca + 3][ra] = av.w;
        *(float4*)&Bs[rw][cw] = wv;
        __syncthreads();
#pragma unroll
        for (int k = 0; k < 16; ++k) {
            const float4 a = *(const float4*)&As[k][ty * 4];
            const float4 b = *(const float4*)&Bs[k][tx * 4];
            acc[0][0] = fmaf(a.x, b.x, acc[0][0]);
            acc[0][1] = fmaf(a.x, b.y, acc[0][1]);
            acc[0][2] = fmaf(a.x, b.z, acc[0][2]);
            acc[0][3] = fmaf(a.x, b.w, acc[0][3]);
            acc[1][0] = fmaf(a.y, b.x, acc[1][0]);
            acc[1][1] = fmaf(a.y, b.y, acc[1][1]);
            acc[1][2] = fmaf(a.y, b.z, acc[1][2]);
            acc[1][3] = fmaf(a.y, b.w, acc[1][3]);
            acc[2][0] = fmaf(a.z, b.x, acc[2][0]);
            acc[2][1] = fmaf(a.z, b.y, acc[2][1]);
            acc[2][2] = fmaf(a.z, b.z, acc[2][2]);
            acc[2][3] = fmaf(a.z, b.w, acc[2][3]);
            acc[3][0] = fmaf(a.w, b.x, acc[3][0]);
            acc[3][1] = fmaf(a.w, b.y, acc[3][1]);
            acc[3][2] = fmaf(a.w, b.z, acc[3][2]);
            acc[3][3] = fmaf(a.w, b.w, acc[3][3]);
        }
        __syncthreads();
    }

    const int row = bm * 64 + ty * 4;
    const int col = bn * 64 + tx * 4;
#pragma unroll
    for (int i = 0; i < 4; ++i) {
#pragma unroll
        for (int j = 0; j < 4; ++j) {
            float v = acc[i][j] + bias[col + j];
            float* cp = &C[(size_t)(row + i) * N + col + j];
            if (MODE == 1) v = gelu_f(v);
            if (MODE == 2) v += *cp;
            *cp = v;
        }
    }
}

// ---- x += layernorm(h) * scale + bias ; one wave per point ----
__global__ __launch_bounds__(256) void ln_res_k(
        const float4* __restrict__ h4, const float* __restrict__ scale,
        const float* __restrict__ bias, float4* __restrict__ x4) {
    const int p = blockIdx.x * 4 + ((int)threadIdx.x >> 6);
    const int lane = (int)threadIdx.x & 63;
    const float4 v = h4[p * 64 + lane];
    float s = v.x + v.y + v.z + v.w;
    float ss = v.x * v.x + v.y * v.y + v.z * v.z + v.w * v.w;
#pragma unroll
    for (int off = 32; off; off >>= 1) {
        s += __shfl_xor(s, off);
        ss += __shfl_xor(ss, off);
    }
    const float mu = s * (1.0f / 256.0f);
    const float var = ss * (1.0f / 256.0f) - mu * mu;
    const float rs = rsqrtf(var + 1e-6f);
    const float4 sc = ((const float4*)scale)[lane];
    const float4 bi = ((const float4*)bias)[lane];
    float4 xv = x4[p * 64 + lane];
    xv.x += (v.x - mu) * rs * sc.x + bi.x;
    xv.y += (v.y - mu) * rs * sc.y + bi.y;
    xv.z += (v.z - mu) * rs * sc.z + bi.z;
    xv.w += (v.w - mu) * rs * sc.w + bi.w;
    x4[p * 64 + lane] = xv;
}

// ---- feat[t][c] = mean over (h,w) of x ----
__global__ void feat_k(const float* __restrict__ x, float* __restrict__ feat) {
    const int t = blockIdx.x;
    const int c = (int)threadIdx.x;
    float s = 0.f;
    const float* xp = x + (size_t)t * 1024 * Cn + c;
    for (int p = 0; p < 1024; ++p) s += xp[(size_t)p * Cn];
    feat[t * Cn + c] = s * (1.0f / 1024.0f);
}

// ---- heads: trajectories + occlusion ----
__global__ __launch_bounds__(256) void heads_k(
        const float* __restrict__ feat, const float* __restrict__ qp,
        const float* __restrict__ traj_w, const float* __restrict__ traj_b,
        const float* __restrict__ occ_w, const float* __restrict__ occ_b,
        float* __restrict__ out) {
    __shared__ float fs[Tn * Cn];
    __shared__ float proj[Tn][3];
    const int tid = (int)threadIdx.x;
    for (int i = tid; i < Tn * Cn; i += 256) fs[i] = feat[i];
    __syncthreads();
    if (tid < 24) {
        const int t = tid / 3, j = tid % 3;
        float s = 0.f;
        for (int c = 0; c < Cn; ++c) {
            const float w = (j < 2) ? traj_w[c * 2 + j] : occ_w[c];
            s += fs[t * Cn + c] * w;
        }
        s += (j < 2) ? traj_b[j] : occ_b[0];
        proj[t][j] = s;
    }
    __syncthreads();
    const int n = tid;  // 0..255
#pragma unroll
    for (int t = 0; t < Tn; ++t) {
        out[(n * Tn + t) * 2 + 0] = proj[t][0] + qp[n * 3 + 1];
        out[(n * Tn + t) * 2 + 1] = proj[t][1] + qp[n * 3 + 2];
        out[4096 + n * Tn + t] = 1.0f / (1.0f + expf(-proj[t][2]));
    }
}

extern "C" void kernel_launch(void* const* d_in, const int* in_sizes, int n_in,
                              void* d_out, int out_size, void* d_ws, size_t ws_size,
                              hipStream_t stream) {
    const float* video = (const float*)d_in[0];
    const float* qp    = (const float*)d_in[1];
    const float* convw = (const float*)d_in[2];
    const float* convb = (const float*)d_in[3];
    const float* Ak    = (const float*)d_in[4];
    const float* Bk    = (const float*)d_in[5];
    const float* ln_s  = (const float*)d_in[6];
    const float* ln_b  = (const float*)d_in[7];
    const float* w1    = (const float*)d_in[8];
    const float* b1    = (const float*)d_in[9];
    const float* w2    = (const float*)d_in[10];
    const float* b2    = (const float*)d_in[11];
    const float* tw    = (const float*)d_in[12];
    const float* tb    = (const float*)d_in[13];
    const float* ow    = (const float*)d_in[14];
    const float* ob    = (const float*)d_in[15];

    float* ws = (float*)d_ws;
    float* x  = ws;                       // 8192*256
    float* h  = ws + 1 * 2097152;
    float* y0 = ws + 2 * 2097152;
    float* y1 = ws + 3 * 2097152;
    float* m  = ws + 4 * 2097152;         // 8192*1024
    float* AT = ws + 4 * 2097152 + 8388608;
    float* BT = AT + NTAP * Cn;
    float* feat = BT + NTAP * Cn;

    // x = video @ conv_w + conv_b   (M=8192, N=256, K=128)
    {
        dim3 g(Cn / 64, Pn / 64);
        gemm_f32_k<0><<<g, dim3(256), 0, stream>>>(video, convw, convb, x, Pn, Cn, CINn);
    }

    for (int i = 0; i < 3; ++i) {
        prep_kernels_k<<<NTAP, Cn, 0, stream>>>(Ak + (size_t)i * Cn * NTAP,
                                                Bk + (size_t)i * Cn * NTAP, AT, BT);
        // h = B (*) x ; y0 = same
        conv_dw_k<<<Tn * Hn, 512, 0, stream>>>((const float4*)x, (const float4*)BT,
                                               (float4*)y0, (float4*)h, 1);
        // 7x: y_k = A (*) y_{k-1} ; h += y_k
        float* bufs[2] = {y0, y1};
        for (int k = 1; k < 8; ++k) {
            const float* s4 = bufs[(k + 1) & 1];
            float* dst = bufs[k & 1];
            conv_dw_k<<<Tn * Hn, 512, 0, stream>>>((const float4*)s4, (const float4*)AT,
                                                   (float4*)dst, (float4*)h, 0);
        }
        // x += LN(h)*scale + bias
        ln_res_k<<<Pn / 4, 256, 0, stream>>>((const float4*)h, ln_s + i * Cn,
                                             ln_b + i * Cn, (float4*)x);
        // m = gelu(x @ w1 + b1)   (M=8192, N=1024, K=256)
        {
            dim3 g(1024 / 64, Pn / 64);
            gemm_f32_k<1><<<g, dim3(256), 0, stream>>>(x, w1 + (size_t)i * Cn * 1024,
                                                       b1 + (size_t)i * 1024, m, Pn, 1024, Cn);
        }
        // x += m @ w2 + b2        (M=8192, N=256, K=1024)
        {
            dim3 g(Cn / 64, Pn / 64);
            gemm_f32_k<2><<<g, dim3(256), 0, stream>>>(m, w2 + (size_t)i * 1024 * Cn,
                                                       b2 + (size_t)i * Cn, x, Pn, Cn, 1024);
        }
    }

    feat_k<<<Tn, Cn, 0, stream>>>(x, feat);
    heads_k<<<1, 256, 0, stream>>>(feat, qp, tw, tb, ow, ob, (float*)d_out);
}

// Round 2
// 566.525 us; speedup vs baseline: 2.2800x; 2.2800x over previous
//
#include <hip/hip_runtime.h>
#include <hip/hip_bf16.h>
#include <math.h>

#define Tn 8
#define Hn 32
#define Wn 32
#define Pn 8192      // Tn*Hn*Wn
#define Cn 256
#define CINn 128
#define NTAP 147     // 3*7*7

typedef short s8v __attribute__((ext_vector_type(8)));   // 8 x bf16 (4 VGPRs)
typedef float f4v __attribute__((ext_vector_type(4)));   // MFMA acc
typedef __hip_bfloat16 bf16;

__device__ __forceinline__ float gelu_f(float v) {
    return 0.5f * v * (1.0f + tanhf(0.7978845608028654f * (v + 0.044715f * v * v * v)));
}

// ---------------- cast f32 -> bf16 (same layout) ----------------
__global__ __launch_bounds__(256) void cast_bf16_k(const float* __restrict__ in,
                                                   bf16* __restrict__ out) {
    const int i = blockIdx.x * 256 + threadIdx.x;
    const float4 v = ((const float4*)in)[i];
    out[i * 4 + 0] = __float2bfloat16(v.x);
    out[i * 4 + 1] = __float2bfloat16(v.y);
    out[i * 4 + 2] = __float2bfloat16(v.z);
    out[i * 4 + 3] = __float2bfloat16(v.w);
}

// ---------------- transpose+cast: in f32 [R][C] -> out bf16 [C][R] ----------------
__global__ __launch_bounds__(256) void tcast_k(const float* __restrict__ in,
                                               bf16* __restrict__ out, int R, int C) {
    __shared__ float tile[32][33];
    const int tid = (int)threadIdx.x, tx = tid & 31, ty = tid >> 5;
    const int rb = blockIdx.y << 5, cb = blockIdx.x << 5;
#pragma unroll
    for (int p = 0; p < 4; ++p)
        tile[ty + p * 8][tx] = in[(size_t)(rb + ty + p * 8) * C + cb + tx];
    __syncthreads();
#pragma unroll
    for (int p = 0; p < 4; ++p)
        out[(size_t)(cb + ty + p * 8) * R + rb + tx] = __float2bfloat16(tile[tx][ty + p * 8]);
}

// ---------------- transpose f32: in [R][C] -> out [C][R] ----------------
__global__ __launch_bounds__(256) void transpose32_k(const float* __restrict__ in,
                                                     float* __restrict__ out, int R, int C) {
    __shared__ float tile[32][33];
    const int tid = (int)threadIdx.x, tx = tid & 31, ty = tid >> 5;
    const int rb = blockIdx.y << 5, cb = blockIdx.x << 5;
#pragma unroll
    for (int p = 0; p < 4; ++p)
        tile[ty + p * 8][tx] = in[(size_t)(rb + ty + p * 8) * C + cb + tx];
    __syncthreads();
#pragma unroll
    for (int p = 0; p < 4; ++p)
        out[(size_t)(cb + ty + p * 8) * R + rb + tx] = tile[tx][ty + p * 8];
}

// ---------------- bf16 MFMA GEMM: C[M,N] = f(A[M,K] @ Wt[N,K]^T + bias) ----------------
// BM=128 fixed, BN in {64,128}; 256 threads = 4 waves in 2x2 grid.
// LDS layout: chunk (k8, m) = 16B of 8 consecutive k at row m -> index k8*BM + m.
// MODE 0: Cf = v ; MODE 1: Cb = bf16(gelu(v)) ; MODE 2: Cf += v
template <int BN, int MODE>
__global__ __launch_bounds__(256) void gemm_bf16_k(
        const bf16* __restrict__ A, const bf16* __restrict__ Wt,
        const float* __restrict__ bias, float* __restrict__ Cf,
        bf16* __restrict__ Cb, int M, int N, int K) {
    constexpr int BM = 128;
    constexpr int NW = BN / 2;     // wave n-extent
    constexpr int NF = BN / 32;    // n-frags per wave
    __shared__ s8v As[4 * BM];
    __shared__ s8v Bs[4 * BN];

    const int tid = (int)threadIdx.x;
    const int lane = tid & 63, wid = tid >> 6;
    const int wm = wid & 1, wn = wid >> 1;
    const int l15 = lane & 15, l4 = lane >> 4;
    const int m0 = blockIdx.y * BM;
    const int n0 = blockIdx.x * BN;

    f4v acc[4][NF];
#pragma unroll
    for (int i = 0; i < 4; ++i)
#pragma unroll
        for (int j = 0; j < NF; ++j)
#pragma unroll
            for (int r = 0; r < 4; ++r) acc[i][j][r] = 0.f;

    // staging coords (hoisted)
    const int am = tid & (BM - 1), ak8 = tid >> 7;           // A chunks tid, tid+256
    const int bn_ = tid % BN, bk8 = tid / BN;                // B chunks tid (+256 if BN=128)
    const bf16* Arow = A + (size_t)(m0 + am) * K + ak8 * 8;
    const bf16* Brow = Wt + (size_t)(n0 + bn_) * K + bk8 * 8;

    for (int kb = 0; kb < K; kb += 32) {
        As[tid]       = *(const s8v*)(Arow + kb);
        As[tid + 256] = *(const s8v*)(Arow + kb + 16);       // k8 + 2
        if (BN == 128) {
            Bs[tid]       = *(const s8v*)(Brow + kb);
            Bs[tid + 256] = *(const s8v*)(Brow + kb + 16);
        } else {
            Bs[tid] = *(const s8v*)(Brow + kb);
        }
        __syncthreads();

        s8v af[4], bfr[NF];
#pragma unroll
        for (int i = 0; i < 4; ++i)
            af[i] = As[l4 * BM + wm * 64 + i * 16 + l15];
#pragma unroll
        for (int j = 0; j < NF; ++j)
            bfr[j] = Bs[l4 * BN + wn * NW + j * 16 + l15];
#pragma unroll
        for (int i = 0; i < 4; ++i)
#pragma unroll
            for (int j = 0; j < NF; ++j)
                acc[i][j] = __builtin_amdgcn_mfma_f32_16x16x32_bf16(af[i], bfr[j], acc[i][j], 0, 0, 0);
        __syncthreads();
    }

    // epilogue: D row = (lane>>4)*4 + reg, col = lane&15  [m89-verified]
#pragma unroll
    for (int i = 0; i < 4; ++i) {
        const int rbase = m0 + wm * 64 + i * 16 + l4 * 4;
#pragma unroll
        for (int j = 0; j < NF; ++j) {
            const int col = n0 + wn * NW + j * 16 + l15;
            const float bv = bias[col];
#pragma unroll
            for (int r = 0; r < 4; ++r) {
                const size_t idx = (size_t)(rbase + r) * N + col;
                const float v = acc[i][j][r] + bv;
                if (MODE == 0) Cf[idx] = v;
                if (MODE == 1) Cb[idx] = __float2bfloat16(gelu_f(v));
                if (MODE == 2) Cf[idx] += v;
            }
        }
    }
}

// ---------------- fused 8-iteration depthwise circular conv SSM ----------------
// One block per channel. Planes in LDS (double-buffered, XOR chunk-swizzled).
// 512 threads: tid = (t*32+h)*2 + half; each thread owns 16 w of one (t,h) row.
__global__ __launch_bounds__(512) void conv_ssm_k(
        const float* __restrict__ xp,   // [C][T*H*W]
        const float* __restrict__ Ak,   // [C][147]
        const float* __restrict__ Bk,   // [C][147]
        float* __restrict__ hpo) {      // [C][T*H*W]
    __shared__ float4 P[2][2048];       // 2 planes, chunk = 4 floats; swizzled
    __shared__ float wA[NTAP], wB[NTAP];

    const int c = blockIdx.x;
    const int tid = (int)threadIdx.x;
    const int row = tid >> 1;            // t*32 + h
    const int half = tid & 1;
    const int t = row >> 5, hh = row & 31;
    const int rs = row & 7;
    const int cb0 = half * 4;            // first owned w-chunk

    if (tid < NTAP) {
        wA[tid] = 0.9f * tanhf(Ak[(size_t)c * NTAP + tid]);
        wB[tid] = Bk[(size_t)c * NTAP + tid];
    }
    {   // load x plane into P[0], coalesced global reads, swizzled LDS writes
        const float4* src = (const float4*)(xp + (size_t)c * Pn);
#pragma unroll
        for (int j = 0; j < 4; ++j) {
            const int g = j * 512 + tid;                       // chunk id 0..2047
            P[0][(g >> 3) * 8 + ((g & 7) ^ ((g >> 3) & 7))] = src[g];
        }
    }
    float hsum[16];
#pragma unroll
    for (int i = 0; i < 16; ++i) hsum[i] = 0.f;
    __syncthreads();

#pragma unroll 1
    for (int it = 0; it < 8; ++it) {
        const float* w = (it == 0) ? wB : wA;
        const float4* srcp = P[it & 1];
        float4* dstp = P[(it & 1) ^ 1];
        float acc[16];
#pragma unroll
        for (int i = 0; i < 16; ++i) acc[i] = 0.f;

#pragma unroll 1
        for (int kh = 0; kh < 7; ++kh) {
            const int hh2 = (hh - kh + 3) & 31;
#pragma unroll
            for (int kt = 0; kt < 3; ++kt) {
                const int sr = ((t - kt + 1) & 7) * 32 + hh2;
                const int srs = sr & 7;
                const int base = sr * 8;
                float r[24];                                  // w = wb-4 .. wb+19 (mod 32)
#pragma unroll
                for (int j = 0; j < 6; ++j) {
                    const int cidx = (cb0 + 7 + j) & 7;       // (cb0-1+j) mod 8
                    const float4 v = srcp[base + (cidx ^ srs)];
                    r[j * 4 + 0] = v.x; r[j * 4 + 1] = v.y;
                    r[j * 4 + 2] = v.z; r[j * 4 + 3] = v.w;
                }
                const float* wp = w + (kt * 7 + kh) * 7;
#pragma unroll
                for (int kw = 0; kw < 7; ++kw) {
                    const float wv = wp[kw];
#pragma unroll
                    for (int wl = 0; wl < 16; ++wl)
                        acc[wl] = fmaf(wv, r[wl + 7 - kw], acc[wl]);
                }
            }
        }
        if (it < 7) {
#pragma unroll
            for (int j = 0; j < 4; ++j)
                dstp[row * 8 + ((cb0 + j) ^ rs)] =
                    make_float4(acc[j * 4], acc[j * 4 + 1], acc[j * 4 + 2], acc[j * 4 + 3]);
        }
#pragma unroll
        for (int i = 0; i < 16; ++i) hsum[i] += acc[i];
        __syncthreads();
    }

    float4* o = (float4*)(hpo + (size_t)c * Pn);
#pragma unroll
    for (int j = 0; j < 4; ++j)
        o[tid * 4 + j] = make_float4(hsum[j * 4], hsum[j * 4 + 1], hsum[j * 4 + 2], hsum[j * 4 + 3]);
}

// ---------------- x += LN(h)*scale + bias ; also emit x in bf16 ----------------
__global__ __launch_bounds__(256) void ln_res_k(
        const float4* __restrict__ h4, const float* __restrict__ scale,
        const float* __restrict__ bias, float4* __restrict__ x4,
        bf16* __restrict__ xb) {
    const int p = blockIdx.x * 4 + ((int)threadIdx.x >> 6);
    const int lane = (int)threadIdx.x & 63;
    const float4 v = h4[p * 64 + lane];
    float s = v.x + v.y + v.z + v.w;
    float ss = v.x * v.x + v.y * v.y + v.z * v.z + v.w * v.w;
#pragma unroll
    for (int off = 32; off; off >>= 1) {
        s += __shfl_xor(s, off);
        ss += __shfl_xor(ss, off);
    }
    const float mu = s * (1.0f / 256.0f);
    const float var = ss * (1.0f / 256.0f) - mu * mu;
    const float rs = rsqrtf(var + 1e-6f);
    const float4 sc = ((const float4*)scale)[lane];
    const float4 bi = ((const float4*)bias)[lane];
    float4 xv = x4[p * 64 + lane];
    xv.x += (v.x - mu) * rs * sc.x + bi.x;
    xv.y += (v.y - mu) * rs * sc.y + bi.y;
    xv.z += (v.z - mu) * rs * sc.z + bi.z;
    xv.w += (v.w - mu) * rs * sc.w + bi.w;
    x4[p * 64 + lane] = xv;
    bf16* xbp = xb + (size_t)p * Cn + lane * 4;
    xbp[0] = __float2bfloat16(xv.x);
    xbp[1] = __float2bfloat16(xv.y);
    xbp[2] = __float2bfloat16(xv.z);
    xbp[3] = __float2bfloat16(xv.w);
}

// ---------------- feat = mean over (h,w) ----------------
__global__ void feat_part_k(const float* __restrict__ x, float* __restrict__ part) {
    const int t = blockIdx.x, sgm = blockIdx.y;   // 8 x 8
    const int c = (int)threadIdx.x;
    float acc = 0.f;
    const float* xp_ = x + ((size_t)t * 1024 + sgm * 128) * Cn + c;
    for (int p = 0; p < 128; ++p) acc += xp_[(size_t)p * Cn];
    part[(t * 8 + sgm) * Cn + c] = acc;
}
__global__ void feat_reduce_k(const float* __restrict__ part, float* __restrict__ feat) {
    const int t = blockIdx.x;
    const int c = (int)threadIdx.x;
    float s = 0.f;
    for (int j = 0; j < 8; ++j) s += part[(t * 8 + j) * Cn + c];
    feat[t * Cn + c] = s * (1.0f / 1024.0f);
}

// ---------------- heads ----------------
__global__ __launch_bounds__(256) void heads_k(
        const float* __restrict__ feat, const float* __restrict__ qp,
        const float* __restrict__ traj_w, const float* __restrict__ traj_b,
        const float* __restrict__ occ_w, const float* __restrict__ occ_b,
        float* __restrict__ out) {
    __shared__ float fs[Tn * Cn];
    __shared__ float proj[Tn][3];
    const int tid = (int)threadIdx.x;
    for (int i = tid; i < Tn * Cn; i += 256) fs[i] = feat[i];
    __syncthreads();
    if (tid < 24) {
        const int t = tid / 3, j = tid % 3;
        float s = 0.f;
        for (int c = 0; c < Cn; ++c) {
            const float w = (j < 2) ? traj_w[c * 2 + j] : occ_w[c];
            s += fs[t * Cn + c] * w;
        }
        s += (j < 2) ? traj_b[j] : occ_b[0];
        proj[t][j] = s;
    }
    __syncthreads();
    const int n = tid;
#pragma unroll
    for (int t = 0; t < Tn; ++t) {
        out[(n * Tn + t) * 2 + 0] = proj[t][0] + qp[n * 3 + 1];
        out[(n * Tn + t) * 2 + 1] = proj[t][1] + qp[n * 3 + 2];
        out[4096 + n * Tn + t] = 1.0f / (1.0f + expf(-proj[t][2]));
    }
}

extern "C" void kernel_launch(void* const* d_in, const int* in_sizes, int n_in,
                              void* d_out, int out_size, void* d_ws, size_t ws_size,
                              hipStream_t stream) {
    const float* video = (const float*)d_in[0];
    const float* qp    = (const float*)d_in[1];
    const float* convw = (const float*)d_in[2];
    const float* convb = (const float*)d_in[3];
    const float* Ak    = (const float*)d_in[4];
    const float* Bk    = (const float*)d_in[5];
    const float* ln_s  = (const float*)d_in[6];
    const float* ln_b  = (const float*)d_in[7];
    const float* w1    = (const float*)d_in[8];
    const float* b1    = (const float*)d_in[9];
    const float* w2    = (const float*)d_in[10];
    const float* b2    = (const float*)d_in[11];
    const float* tw    = (const float*)d_in[12];
    const float* tb    = (const float*)d_in[13];
    const float* ow    = (const float*)d_in[14];
    const float* ob    = (const float*)d_in[15];

    char* wsb = (char*)d_ws;
    float* x   = (float*)wsb;            wsb += (size_t)Pn * Cn * 4;       // 8 MB
    float* h   = (float*)wsb;            wsb += (size_t)Pn * Cn * 4;
    float* xpl = (float*)wsb;            wsb += (size_t)Pn * Cn * 4;
    float* hpl = (float*)wsb;            wsb += (size_t)Pn * Cn * 4;
    bf16*  xb  = (bf16*)wsb;             wsb += (size_t)Pn * Cn * 2;       // 4 MB
    bf16*  mb  = (bf16*)wsb;             wsb += (size_t)Pn * 1024 * 2;     // 16 MB
    bf16*  vb  = (bf16*)wsb;             wsb += (size_t)Pn * CINn * 2;     // 2 MB
    bf16*  cwT = (bf16*)wsb;             wsb += (size_t)Cn * CINn * 2;
    bf16*  w1T = (bf16*)wsb;             wsb += (size_t)3 * 1024 * Cn * 2;
    bf16*  w2T = (bf16*)wsb;             wsb += (size_t)3 * Cn * 1024 * 2;
    float* feat = (float*)wsb;           wsb += (size_t)Tn * Cn * 4;
    float* part = (float*)wsb;           wsb += (size_t)64 * Cn * 4;

    // ---- weight/activation prep (runs every launch; ~15 us total) ----
    cast_bf16_k<<<(Pn * CINn) / 1024, 256, 0, stream>>>(video, vb);
    tcast_k<<<dim3(Cn / 32, CINn / 32), 256, 0, stream>>>(convw, cwT, CINn, Cn);
    for (int i = 0; i < 3; ++i) {
        tcast_k<<<dim3(1024 / 32, Cn / 32), 256, 0, stream>>>(
            w1 + (size_t)i * Cn * 1024, w1T + (size_t)i * 1024 * Cn, Cn, 1024);
        tcast_k<<<dim3(Cn / 32, 1024 / 32), 256, 0, stream>>>(
            w2 + (size_t)i * 1024 * Cn, w2T + (size_t)i * Cn * 1024, 1024, Cn);
    }

    // x = video @ conv_w + conv_b   (M=8192, N=256, K=128)
    gemm_bf16_k<64, 0><<<dim3(Cn / 64, Pn / 128), 256, 0, stream>>>(
        vb, cwT, convb, x, nullptr, Pn, Cn, CINn);

    for (int i = 0; i < 3; ++i) {
        // x -> channel planes
        transpose32_k<<<dim3(Cn / 32, Pn / 32), 256, 0, stream>>>(x, xpl, Pn, Cn);
        // all 8 circular convs + running sum, one block per channel
        conv_ssm_k<<<Cn, 512, 0, stream>>>(xpl, Ak + (size_t)i * Cn * NTAP,
                                           Bk + (size_t)i * Cn * NTAP, hpl);
        // planes -> [p][c]
        transpose32_k<<<dim3(Pn / 32, Cn / 32), 256, 0, stream>>>(hpl, h, Cn, Pn);
        // x += LN(h)*s + b ; emit xb (bf16)
        ln_res_k<<<Pn / 4, 256, 0, stream>>>((const float4*)h, ln_s + i * Cn,
                                             ln_b + i * Cn, (float4*)x, xb);
        // mb = bf16(gelu(xb @ w1T^T + b1))   (M=8192, N=1024, K=256)
        gemm_bf16_k<128, 1><<<dim3(1024 / 128, Pn / 128), 256, 0, stream>>>(
            xb, w1T + (size_t)i * 1024 * Cn, b1 + (size_t)i * 1024, nullptr, mb,
            Pn, 1024, Cn);
        // x += mb @ w2T^T + b2               (M=8192, N=256, K=1024)
        gemm_bf16_k<64, 2><<<dim3(Cn / 64, Pn / 128), 256, 0, stream>>>(
            mb, w2T + (size_t)i * Cn * 1024, b2 + (size_t)i * Cn, x, nullptr,
            Pn, Cn, 1024);
    }

    feat_part_k<<<dim3(Tn, 8), 256, 0, stream>>>(x, part);
    feat_reduce_k<<<Tn, 256, 0, stream>>>(part, feat);
    heads_k<<<1, 256, 0, stream>>>(feat, qp, tw, tb, ow, ob, (float*)d_out);
}

// Round 4
// 520.994 us; speedup vs baseline: 2.4793x; 1.0874x over previous
//
#include <hip/hip_runtime.h>
#include <hip/hip_bf16.h>
#include <math.h>

#define Tn 8
#define Hn 32
#define Wn 32
#define Pn 8192      // Tn*Hn*Wn
#define Cn 256
#define CINn 128
#define NTAP 147     // 3*7*7

typedef short s8v __attribute__((ext_vector_type(8)));   // 8 x bf16 (4 VGPRs)
typedef float f4v __attribute__((ext_vector_type(4)));   // MFMA acc
typedef __hip_bfloat16 bf16;

__device__ __forceinline__ float gelu_f(float v) {
    return 0.5f * v * (1.0f + tanhf(0.7978845608028654f * (v + 0.044715f * v * v * v)));
}

// ---------------- cast f32 -> bf16 (same layout) ----------------
__global__ __launch_bounds__(256) void cast_bf16_k(const float* __restrict__ in,
                                                   bf16* __restrict__ out) {
    const int i = blockIdx.x * 256 + threadIdx.x;
    const float4 v = ((const float4*)in)[i];
    out[i * 4 + 0] = __float2bfloat16(v.x);
    out[i * 4 + 1] = __float2bfloat16(v.y);
    out[i * 4 + 2] = __float2bfloat16(v.z);
    out[i * 4 + 3] = __float2bfloat16(v.w);
}

// ---------------- transpose+cast: in f32 [R][C] -> out bf16 [C][R] ----------------
__global__ __launch_bounds__(256) void tcast_k(const float* __restrict__ in,
                                               bf16* __restrict__ out, int R, int C) {
    __shared__ float tile[32][33];
    const int tid = (int)threadIdx.x, tx = tid & 31, ty = tid >> 5;
    const int rb = blockIdx.y << 5, cb = blockIdx.x << 5;
#pragma unroll
    for (int p = 0; p < 4; ++p)
        tile[ty + p * 8][tx] = in[(size_t)(rb + ty + p * 8) * C + cb + tx];
    __syncthreads();
#pragma unroll
    for (int p = 0; p < 4; ++p)
        out[(size_t)(cb + ty + p * 8) * R + rb + tx] = __float2bfloat16(tile[tx][ty + p * 8]);
}

// ---------------- transpose f32: in [R][C] -> out [C][R] ----------------
__global__ __launch_bounds__(256) void transpose32_k(const float* __restrict__ in,
                                                     float* __restrict__ out, int R, int C) {
    __shared__ float tile[32][33];
    const int tid = (int)threadIdx.x, tx = tid & 31, ty = tid >> 5;
    const int rb = blockIdx.y << 5, cb = blockIdx.x << 5;
#pragma unroll
    for (int p = 0; p < 4; ++p)
        tile[ty + p * 8][tx] = in[(size_t)(rb + ty + p * 8) * C + cb + tx];
    __syncthreads();
#pragma unroll
    for (int p = 0; p < 4; ++p)
        out[(size_t)(cb + ty + p * 8) * R + rb + tx] = tile[tx][ty + p * 8];
}

// ---------------- bf16 MFMA GEMM: C[M,N] = f(A[M,K] @ Wt[N,K]^T + bias) ----------------
template <int BN, int MODE>
__global__ __launch_bounds__(256) void gemm_bf16_k(
        const bf16* __restrict__ A, const bf16* __restrict__ Wt,
        const float* __restrict__ bias, float* __restrict__ Cf,
        bf16* __restrict__ Cb, int M, int N, int K) {
    constexpr int BM = 128;
    constexpr int NW = BN / 2;     // wave n-extent
    constexpr int NF = BN / 32;    // n-frags per wave
    __shared__ s8v As[4 * BM];
    __shared__ s8v Bs[4 * BN];

    const int tid = (int)threadIdx.x;
    const int lane = tid & 63, wid = tid >> 6;
    const int wm = wid & 1, wn = wid >> 1;
    const int l15 = lane & 15, l4 = lane >> 4;
    const int m0 = blockIdx.y * BM;
    const int n0 = blockIdx.x * BN;

    f4v acc[4][NF];
#pragma unroll
    for (int i = 0; i < 4; ++i)
#pragma unroll
        for (int j = 0; j < NF; ++j)
#pragma unroll
            for (int r = 0; r < 4; ++r) acc[i][j][r] = 0.f;

    const int am = tid & (BM - 1), ak8 = tid >> 7;
    const int bn_ = tid % BN, bk8 = tid / BN;
    const bf16* Arow = A + (size_t)(m0 + am) * K + ak8 * 8;
    const bf16* Brow = Wt + (size_t)(n0 + bn_) * K + bk8 * 8;

    for (int kb = 0; kb < K; kb += 32) {
        As[tid]       = *(const s8v*)(Arow + kb);
        As[tid + 256] = *(const s8v*)(Arow + kb + 16);
        if (BN == 128) {
            Bs[tid]       = *(const s8v*)(Brow + kb);
            Bs[tid + 256] = *(const s8v*)(Brow + kb + 16);
        } else {
            Bs[tid] = *(const s8v*)(Brow + kb);
        }
        __syncthreads();

        s8v af[4], bfr[NF];
#pragma unroll
        for (int i = 0; i < 4; ++i)
            af[i] = As[l4 * BM + wm * 64 + i * 16 + l15];
#pragma unroll
        for (int j = 0; j < NF; ++j)
            bfr[j] = Bs[l4 * BN + wn * NW + j * 16 + l15];
#pragma unroll
        for (int i = 0; i < 4; ++i)
#pragma unroll
            for (int j = 0; j < NF; ++j)
                acc[i][j] = __builtin_amdgcn_mfma_f32_16x16x32_bf16(af[i], bfr[j], acc[i][j], 0, 0, 0);
        __syncthreads();
    }

#pragma unroll
    for (int i = 0; i < 4; ++i) {
        const int rbase = m0 + wm * 64 + i * 16 + l4 * 4;
#pragma unroll
        for (int j = 0; j < NF; ++j) {
            const int col = n0 + wn * NW + j * 16 + l15;
            const float bv = bias[col];
#pragma unroll
            for (int r = 0; r < 4; ++r) {
                const size_t idx = (size_t)(rbase + r) * N + col;
                const float v = acc[i][j][r] + bv;
                if (MODE == 0) Cf[idx] = v;
                if (MODE == 1) Cb[idx] = __float2bfloat16(gelu_f(v));
                if (MODE == 2) Cf[idx] += v;
            }
        }
    }
}

// ---------------- fused 8-iteration depthwise circular conv SSM ----------------
// One block (256 threads) per channel. Thread owns one full (t,h) row of 32 w.
// 3 LDS plane buffers rotate (read buf k%3, write (k+1)%3) -> 1 sync/iter.
// Plane layout: chunk c (float4) of row r at index r*8 + (c ^ (r&7))  [XOR swizzle].
#define SF(S, i) (((i) & 3) == 0 ? S[(i) >> 2].x : ((i) & 3) == 1 ? S[(i) >> 2].y \
                : ((i) & 3) == 2 ? S[(i) >> 2].z : S[(i) >> 2].w)

#define LOADS(S, body) do {                                                   \
    const int bb_ = (body);                                                   \
    const int kt_ = bb_ < 7 ? 0 : (bb_ < 14 ? 1 : 2);                         \
    const int kh_ = bb_ - kt_ * 7;                                            \
    const int sr_ = (((t - kt_ + 9) & 7) << 5) + ((hh - kh_ + 35) & 31);      \
    const int rb_ = sr_ * 8, rx_ = sr_ & 7;                                   \
    S[0] = sp[rb_ + (0 ^ rx_)];  S[1] = sp[rb_ + (1 ^ rx_)];                  \
    S[2] = sp[rb_ + (2 ^ rx_)];  S[3] = sp[rb_ + (3 ^ rx_)];                  \
    S[4] = sp[rb_ + (4 ^ rx_)];  S[5] = sp[rb_ + (5 ^ rx_)];                  \
    S[6] = sp[rb_ + (6 ^ rx_)];  S[7] = sp[rb_ + (7 ^ rx_)];                  \
} while (0)

#define COMPUTE(S, body) do {                                                 \
    const float4 wq0_ = *(const float4*)&wP[wbase + (body) * 8];              \
    const float4 wq1_ = *(const float4*)&wP[wbase + (body) * 8 + 4];          \
    const float wv_[7] = {wq0_.x, wq0_.y, wq0_.z, wq0_.w,                     \
                          wq1_.x, wq1_.y, wq1_.z};                            \
    _Pragma("unroll")                                                         \
    for (int kw_ = 0; kw_ < 7; ++kw_) {                                       \
        _Pragma("unroll")                                                     \
        for (int ww_ = 0; ww_ < 32; ++ww_) {                                  \
            const int ix_ = (ww_ - kw_ + 35) & 31;                            \
            acc[ww_] = fmaf(wv_[kw_], SF(S, ix_), acc[ww_]);                  \
        }                                                                     \
    }                                                                         \
} while (0)

__global__ __launch_bounds__(256) void conv_ssm_k(
        const float* __restrict__ xp,   // [C][8192]
        const float* __restrict__ Ak,   // [C][147]
        const float* __restrict__ Bk,   // [C][147]
        float* __restrict__ hpo) {      // [C][8192]
    __shared__ float4 P[3][2048];
    __shared__ float wP[2 * 21 * 8];    // [sel(B=0,A=1)][body][kw], 8-padded

    const int c = blockIdx.x;
    const int tid = (int)threadIdx.x;
    const int t = tid >> 5, hh = tid & 31;

    if (tid < NTAP) {
        const int body = tid / 7, kw = tid % 7;
        wP[body * 8 + kw] = Bk[(size_t)c * NTAP + tid];
        wP[168 + body * 8 + kw] = 0.9f * tanhf(Ak[(size_t)c * NTAP + tid]);
    }
    {   // stage x plane: coalesced global reads, swizzled LDS writes
        const float4* src = (const float4*)(xp + (size_t)c * Pn);
#pragma unroll
        for (int j = 0; j < 8; ++j) {
            const int g = j * 256 + tid;
            P[0][(g >> 3) * 8 + ((g & 7) ^ ((g >> 3) & 7))] = src[g];
        }
    }
    float hsum[32];
#pragma unroll
    for (int i = 0; i < 32; ++i) hsum[i] = 0.f;
    __syncthreads();

    const int rs = tid & 7;
#pragma unroll 1
    for (int it = 0; it < 8; ++it) {
        const int wbase = (it == 0) ? 0 : 168;
        const float4* sp = P[it % 3];
        float4* dp = P[(it + 1) % 3];
        float acc[32];
#pragma unroll
        for (int i = 0; i < 32; ++i) acc[i] = 0.f;

        float4 sA[8], sB[8];
        LOADS(sA, 0);
#pragma unroll 1
        for (int b = 0; b < 20; b += 2) {
            LOADS(sB, b + 1);
            COMPUTE(sA, b);
            LOADS(sA, b + 2);
            COMPUTE(sB, b + 1);
        }
        COMPUTE(sA, 20);

#pragma unroll
        for (int i = 0; i < 32; ++i) hsum[i] += acc[i];
        if (it < 7) {
#pragma unroll
            for (int j = 0; j < 8; ++j)          // ALL 8 chunks (round-3 bug: wrote only 4)
                dp[tid * 8 + (j ^ rs)] =
                    make_float4(acc[j * 4], acc[j * 4 + 1], acc[j * 4 + 2], acc[j * 4 + 3]);
        }
        __syncthreads();
    }

    float4* o = (float4*)(hpo + (size_t)c * Pn + tid * 32);
#pragma unroll
    for (int j = 0; j < 8; ++j)
        o[j] = make_float4(hsum[j * 4], hsum[j * 4 + 1], hsum[j * 4 + 2], hsum[j * 4 + 3]);
}

// ---------------- x += LN(h)*scale + bias ; also emit x in bf16 ----------------
__global__ __launch_bounds__(256) void ln_res_k(
        const float4* __restrict__ h4, const float* __restrict__ scale,
        const float* __restrict__ bias, float4* __restrict__ x4,
        bf16* __restrict__ xb) {
    const int p = blockIdx.x * 4 + ((int)threadIdx.x >> 6);
    const int lane = (int)threadIdx.x & 63;
    const float4 v = h4[p * 64 + lane];
    float s = v.x + v.y + v.z + v.w;
    float ss = v.x * v.x + v.y * v.y + v.z * v.z + v.w * v.w;
#pragma unroll
    for (int off = 32; off; off >>= 1) {
        s += __shfl_xor(s, off);
        ss += __shfl_xor(ss, off);
    }
    const float mu = s * (1.0f / 256.0f);
    const float var = ss * (1.0f / 256.0f) - mu * mu;
    const float rs = rsqrtf(var + 1e-6f);
    const float4 sc = ((const float4*)scale)[lane];
    const float4 bi = ((const float4*)bias)[lane];
    float4 xv = x4[p * 64 + lane];
    xv.x += (v.x - mu) * rs * sc.x + bi.x;
    xv.y += (v.y - mu) * rs * sc.y + bi.y;
    xv.z += (v.z - mu) * rs * sc.z + bi.z;
    xv.w += (v.w - mu) * rs * sc.w + bi.w;
    x4[p * 64 + lane] = xv;
    bf16* xbp = xb + (size_t)p * Cn + lane * 4;
    xbp[0] = __float2bfloat16(xv.x);
    xbp[1] = __float2bfloat16(xv.y);
    xbp[2] = __float2bfloat16(xv.z);
    xbp[3] = __float2bfloat16(xv.w);
}

// ---------------- feat = mean over (h,w) ----------------
__global__ void feat_part_k(const float* __restrict__ x, float* __restrict__ part) {
    const int t = blockIdx.x, sgm = blockIdx.y;
    const int c = (int)threadIdx.x;
    float acc = 0.f;
    const float* xp_ = x + ((size_t)t * 1024 + sgm * 128) * Cn + c;
    for (int p = 0; p < 128; ++p) acc += xp_[(size_t)p * Cn];
    part[(t * 8 + sgm) * Cn + c] = acc;
}
__global__ void feat_reduce_k(const float* __restrict__ part, float* __restrict__ feat) {
    const int t = blockIdx.x;
    const int c = (int)threadIdx.x;
    float s = 0.f;
    for (int j = 0; j < 8; ++j) s += part[(t * 8 + j) * Cn + c];
    feat[t * Cn + c] = s * (1.0f / 1024.0f);
}

// ---------------- heads ----------------
__global__ __launch_bounds__(256) void heads_k(
        const float* __restrict__ feat, const float* __restrict__ qp,
        const float* __restrict__ traj_w, const float* __restrict__ traj_b,
        const float* __restrict__ occ_w, const float* __restrict__ occ_b,
        float* __restrict__ out) {
    __shared__ float fs[Tn * Cn];
    __shared__ float proj[Tn][3];
    const int tid = (int)threadIdx.x;
    for (int i = tid; i < Tn * Cn; i += 256) fs[i] = feat[i];
    __syncthreads();
    if (tid < 24) {
        const int t = tid / 3, j = tid % 3;
        float s = 0.f;
        for (int c = 0; c < Cn; ++c) {
            const float w = (j < 2) ? traj_w[c * 2 + j] : occ_w[c];
            s += fs[t * Cn + c] * w;
        }
        s += (j < 2) ? traj_b[j] : occ_b[0];
        proj[t][j] = s;
    }
    __syncthreads();
    const int n = tid;
#pragma unroll
    for (int t = 0; t < Tn; ++t) {
        out[(n * Tn + t) * 2 + 0] = proj[t][0] + qp[n * 3 + 1];
        out[(n * Tn + t) * 2 + 1] = proj[t][1] + qp[n * 3 + 2];
        out[4096 + n * Tn + t] = 1.0f / (1.0f + expf(-proj[t][2]));
    }
}

extern "C" void kernel_launch(void* const* d_in, const int* in_sizes, int n_in,
                              void* d_out, int out_size, void* d_ws, size_t ws_size,
                              hipStream_t stream) {
    const float* video = (const float*)d_in[0];
    const float* qp    = (const float*)d_in[1];
    const float* convw = (const float*)d_in[2];
    const float* convb = (const float*)d_in[3];
    const float* Ak    = (const float*)d_in[4];
    const float* Bk    = (const float*)d_in[5];
    const float* ln_s  = (const float*)d_in[6];
    const float* ln_b  = (const float*)d_in[7];
    const float* w1    = (const float*)d_in[8];
    const float* b1    = (const float*)d_in[9];
    const float* w2    = (const float*)d_in[10];
    const float* b2    = (const float*)d_in[11];
    const float* tw    = (const float*)d_in[12];
    const float* tb    = (const float*)d_in[13];
    const float* ow    = (const float*)d_in[14];
    const float* ob    = (const float*)d_in[15];

    char* wsb = (char*)d_ws;
    float* x   = (float*)wsb;            wsb += (size_t)Pn * Cn * 4;
    float* h   = (float*)wsb;            wsb += (size_t)Pn * Cn * 4;
    float* xpl = (float*)wsb;            wsb += (size_t)Pn * Cn * 4;
    float* hpl = (float*)wsb;            wsb += (size_t)Pn * Cn * 4;
    bf16*  xb  = (bf16*)wsb;             wsb += (size_t)Pn * Cn * 2;
    bf16*  mb  = (bf16*)wsb;             wsb += (size_t)Pn * 1024 * 2;
    bf16*  vb  = (bf16*)wsb;             wsb += (size_t)Pn * CINn * 2;
    bf16*  cwT = (bf16*)wsb;             wsb += (size_t)Cn * CINn * 2;
    bf16*  w1T = (bf16*)wsb;             wsb += (size_t)3 * 1024 * Cn * 2;
    bf16*  w2T = (bf16*)wsb;             wsb += (size_t)3 * Cn * 1024 * 2;
    float* feat = (float*)wsb;           wsb += (size_t)Tn * Cn * 4;
    float* part = (float*)wsb;           wsb += (size_t)64 * Cn * 4;

    cast_bf16_k<<<(Pn * CINn) / 1024, 256, 0, stream>>>(video, vb);
    tcast_k<<<dim3(Cn / 32, CINn / 32), 256, 0, stream>>>(convw, cwT, CINn, Cn);
    for (int i = 0; i < 3; ++i) {
        tcast_k<<<dim3(1024 / 32, Cn / 32), 256, 0, stream>>>(
            w1 + (size_t)i * Cn * 1024, w1T + (size_t)i * 1024 * Cn, Cn, 1024);
        tcast_k<<<dim3(Cn / 32, 1024 / 32), 256, 0, stream>>>(
            w2 + (size_t)i * 1024 * Cn, w2T + (size_t)i * Cn * 1024, 1024, Cn);
    }

    gemm_bf16_k<64, 0><<<dim3(Cn / 64, Pn / 128), 256, 0, stream>>>(
        vb, cwT, convb, x, nullptr, Pn, Cn, CINn);

    for (int i = 0; i < 3; ++i) {
        transpose32_k<<<dim3(Cn / 32, Pn / 32), 256, 0, stream>>>(x, xpl, Pn, Cn);
        conv_ssm_k<<<Cn, 256, 0, stream>>>(xpl, Ak + (size_t)i * Cn * NTAP,
                                           Bk + (size_t)i * Cn * NTAP, hpl);
        transpose32_k<<<dim3(Pn / 32, Cn / 32), 256, 0, stream>>>(hpl, h, Cn, Pn);
        ln_res_k<<<Pn / 4, 256, 0, stream>>>((const float4*)h, ln_s + i * Cn,
                                             ln_b + i * Cn, (float4*)x, xb);
        gemm_bf16_k<128, 1><<<dim3(1024 / 128, Pn / 128), 256, 0, stream>>>(
            xb, w1T + (size_t)i * 1024 * Cn, b1 + (size_t)i * 1024, nullptr, mb,
            Pn, 1024, Cn);
        gemm_bf16_k<64, 2><<<dim3(Cn / 64, Pn / 128), 256, 0, stream>>>(
            mb, w2T + (size_t)i * Cn * 1024, b2 + (size_t)i * Cn, x, nullptr,
            Pn, Cn, 1024);
    }

    feat_part_k<<<dim3(Tn, 8), 256, 0, stream>>>(x, part);
    feat_reduce_k<<<Tn, 256, 0, stream>>>(part, feat);
    heads_k<<<1, 256, 0, stream>>>(feat, qp, tw, tb, ow, ob, (float*)d_out);
}